// Round 1
// baseline (2398.709 us; speedup 1.0000x reference)
//
#include <hip/hip_runtime.h>
#include <math.h>

#define SEQ   2048
#define CDIM  2048
#define NHEAD 16
#define DHEAD 128
// 1/sqrt(2048)
#define SCALE 0.02209708691207961f

// C[m,n] = sum_k A[m,k]*W[n,k] + bias[n]   (A: MxK row-major, W: NxK row-major)
__global__ __launch_bounds__(256) void gemm_bias_nt(
    const float* __restrict__ A, const float* __restrict__ W,
    const float* __restrict__ bias, float* __restrict__ out)
{
    __shared__ float As[64][33];
    __shared__ float Ws[64][33];
    const int tid = threadIdx.x;
    const int tx = tid & 15, ty = tid >> 4;
    const int m0 = blockIdx.y * 64, n0 = blockIdx.x * 64;
    const int lrow = tid >> 2;          // 0..63
    const int lcol = (tid & 3) * 8;     // 0,8,16,24

    float acc[4][4];
    #pragma unroll
    for (int i = 0; i < 4; ++i)
        #pragma unroll
        for (int j = 0; j < 4; ++j) acc[i][j] = 0.f;

    for (int k0 = 0; k0 < CDIM; k0 += 32) {
        float4 a0 = *reinterpret_cast<const float4*>(&A[(size_t)(m0 + lrow) * CDIM + k0 + lcol]);
        float4 a1 = *reinterpret_cast<const float4*>(&A[(size_t)(m0 + lrow) * CDIM + k0 + lcol + 4]);
        float4 w0 = *reinterpret_cast<const float4*>(&W[(size_t)(n0 + lrow) * CDIM + k0 + lcol]);
        float4 w1 = *reinterpret_cast<const float4*>(&W[(size_t)(n0 + lrow) * CDIM + k0 + lcol + 4]);
        As[lrow][lcol+0]=a0.x; As[lrow][lcol+1]=a0.y; As[lrow][lcol+2]=a0.z; As[lrow][lcol+3]=a0.w;
        As[lrow][lcol+4]=a1.x; As[lrow][lcol+5]=a1.y; As[lrow][lcol+6]=a1.z; As[lrow][lcol+7]=a1.w;
        Ws[lrow][lcol+0]=w0.x; Ws[lrow][lcol+1]=w0.y; Ws[lrow][lcol+2]=w0.z; Ws[lrow][lcol+3]=w0.w;
        Ws[lrow][lcol+4]=w1.x; Ws[lrow][lcol+5]=w1.y; Ws[lrow][lcol+6]=w1.z; Ws[lrow][lcol+7]=w1.w;
        __syncthreads();
        #pragma unroll 8
        for (int kk = 0; kk < 32; ++kk) {
            float av[4], wv[4];
            #pragma unroll
            for (int i = 0; i < 4; ++i) av[i] = As[ty*4+i][kk];
            #pragma unroll
            for (int j = 0; j < 4; ++j) wv[j] = Ws[tx + 16*j][kk];
            #pragma unroll
            for (int i = 0; i < 4; ++i)
                #pragma unroll
                for (int j = 0; j < 4; ++j)
                    acc[i][j] += av[i] * wv[j];
        }
        __syncthreads();
    }

    #pragma unroll
    for (int i = 0; i < 4; ++i) {
        const int m = m0 + ty*4 + i;
        #pragma unroll
        for (int j = 0; j < 4; ++j) {
            const int n = n0 + tx + 16*j;
            out[(size_t)m * CDIM + n] = acc[i][j] + bias[n];
        }
    }
}

// Apply RoPE in place to q (blockIdx.y==0) and k (blockIdx.y==1).
__global__ void rope_kernel(float* __restrict__ q, float* __restrict__ k,
                            const float* __restrict__ cosT, const float* __restrict__ sinT)
{
    const int idx = blockIdx.x * 256 + threadIdx.x;   // pair index, T*C/2 total
    float* buf = blockIdx.y ? k : q;
    const int t  = idx >> 10;        // / (CDIM/2)
    const int p  = idx & 1023;
    const int h  = p >> 6;
    const int fi = p & 63;
    const float c = cosT[t*64 + fi];
    const float s = sinT[t*64 + fi];
    const size_t base = (size_t)t * CDIM + h * DHEAD + 2*fi;
    const float r  = buf[base];
    const float im = buf[base + 1];
    buf[base]     = r * c - im * s;
    buf[base + 1] = r * s + im * c;
}

// One block per (q-tile of 64 rows, head). fp32 flash attention with causal mask.
__global__ __launch_bounds__(256) void flash_attn(
    const float* __restrict__ q, const float* __restrict__ k,
    const float* __restrict__ v, float* __restrict__ o)
{
    __shared__ float Qs[64][129];
    __shared__ float Ks[64][129];
    __shared__ float Vs[64][129];
    __shared__ float Ss[64][65];
    __shared__ float rowM[64], rowL[64], rowF[64];

    const int tid = threadIdx.x;
    const int tx = tid & 15, ty = tid >> 4;
    const int h = blockIdx.y, qt = blockIdx.x;
    const int q0 = qt * 64;

    // load Q tile (64 x 128)
    #pragma unroll
    for (int e = 0; e < 8; ++e) {
        const int f = tid + 256*e;
        const int r = f >> 5;
        const int c0 = (f & 31) * 4;
        float4 val = *reinterpret_cast<const float4*>(&q[(size_t)(q0 + r) * CDIM + h*DHEAD + c0]);
        Qs[r][c0+0]=val.x; Qs[r][c0+1]=val.y; Qs[r][c0+2]=val.z; Qs[r][c0+3]=val.w;
    }
    if (tid < 64) { rowM[tid] = -INFINITY; rowL[tid] = 0.f; }

    float oacc[4][8];
    #pragma unroll
    for (int i = 0; i < 4; ++i)
        #pragma unroll
        for (int j = 0; j < 8; ++j) oacc[i][j] = 0.f;

    for (int kt = 0; kt <= qt; ++kt) {
        __syncthreads();   // Q visible (1st iter); prev PV done before K/V/S overwrite
        #pragma unroll
        for (int e = 0; e < 8; ++e) {
            const int f = tid + 256*e;
            const int r = f >> 5;
            const int c0 = (f & 31) * 4;
            float4 kl = *reinterpret_cast<const float4*>(&k[(size_t)(kt*64 + r) * CDIM + h*DHEAD + c0]);
            float4 vl = *reinterpret_cast<const float4*>(&v[(size_t)(kt*64 + r) * CDIM + h*DHEAD + c0]);
            Ks[r][c0+0]=kl.x; Ks[r][c0+1]=kl.y; Ks[r][c0+2]=kl.z; Ks[r][c0+3]=kl.w;
            Vs[r][c0+0]=vl.x; Vs[r][c0+1]=vl.y; Vs[r][c0+2]=vl.z; Vs[r][c0+3]=vl.w;
        }
        __syncthreads();

        // S = Q K^T (64x64, inner 128)
        float sacc[4][4];
        #pragma unroll
        for (int i = 0; i < 4; ++i)
            #pragma unroll
            for (int j = 0; j < 4; ++j) sacc[i][j] = 0.f;
        #pragma unroll 4
        for (int kk = 0; kk < 128; ++kk) {
            float qv[4], kv[4];
            #pragma unroll
            for (int i = 0; i < 4; ++i) qv[i] = Qs[ty*4+i][kk];
            #pragma unroll
            for (int j = 0; j < 4; ++j) kv[j] = Ks[tx + 16*j][kk];
            #pragma unroll
            for (int i = 0; i < 4; ++i)
                #pragma unroll
                for (int j = 0; j < 4; ++j)
                    sacc[i][j] += qv[i] * kv[j];
        }
        #pragma unroll
        for (int i = 0; i < 4; ++i) {
            const int r = ty*4 + i;
            #pragma unroll
            for (int j = 0; j < 4; ++j) {
                const int c = tx + 16*j;
                float sval = sacc[i][j] * SCALE;
                if (kt == qt && (kt*64 + c) > (q0 + r)) sval = -INFINITY;
                Ss[r][c] = sval;
            }
        }
        __syncthreads();

        // online softmax (wave 0, one lane per row)
        if (tid < 64) {
            const int r = tid;
            float mt = -INFINITY;
            for (int c2 = 0; c2 < 64; ++c2) mt = fmaxf(mt, Ss[r][c2]);
            const float mold = rowM[r];
            const float mnew = fmaxf(mold, mt);
            const float fac = expf(mold - mnew);
            float ls = 0.f;
            for (int c2 = 0; c2 < 64; ++c2) {
                const float p = expf(Ss[r][c2] - mnew);
                Ss[r][c2] = p;
                ls += p;
            }
            rowL[r] = rowL[r] * fac + ls;
            rowM[r] = mnew;
            rowF[r] = fac;
        }
        __syncthreads();

        // rescale O, then O += P V
        float fr[4];
        #pragma unroll
        for (int i = 0; i < 4; ++i) fr[i] = rowF[ty*4+i];
        #pragma unroll
        for (int i = 0; i < 4; ++i)
            #pragma unroll
            for (int j = 0; j < 8; ++j) oacc[i][j] *= fr[i];
        #pragma unroll 4
        for (int kk = 0; kk < 64; ++kk) {
            float pv[4], vv[8];
            #pragma unroll
            for (int i = 0; i < 4; ++i) pv[i] = Ss[ty*4+i][kk];
            #pragma unroll
            for (int j = 0; j < 8; ++j) vv[j] = Vs[kk][tx + 16*j];
            #pragma unroll
            for (int i = 0; i < 4; ++i)
                #pragma unroll
                for (int j = 0; j < 8; ++j)
                    oacc[i][j] += pv[i] * vv[j];
        }
    }

    #pragma unroll
    for (int i = 0; i < 4; ++i) {
        const int r = ty*4 + i;
        const float inv = 1.f / rowL[r];
        #pragma unroll
        for (int j = 0; j < 8; ++j) {
            o[(size_t)(q0 + r) * CDIM + h*DHEAD + tx + 16*j] = oacc[i][j] * inv;
        }
    }
}

extern "C" void kernel_launch(void* const* d_in, const int* in_sizes, int n_in,
                              void* d_out, int out_size, void* d_ws, size_t ws_size,
                              hipStream_t stream) {
    const float* x    = (const float*)d_in[0];
    const float* wq   = (const float*)d_in[1];
    const float* bq   = (const float*)d_in[2];
    const float* wk   = (const float*)d_in[3];
    const float* bk   = (const float*)d_in[4];
    const float* wv   = (const float*)d_in[5];
    const float* bv   = (const float*)d_in[6];
    const float* wp   = (const float*)d_in[7];
    const float* bp   = (const float*)d_in[8];
    const float* cosT = (const float*)d_in[9];
    const float* sinT = (const float*)d_in[10];
    float* out = (float*)d_out;

    const size_t mat = (size_t)SEQ * CDIM;
    float* q  = (float*)d_ws;
    float* k  = q + mat;
    float* v  = k + mat;
    float* ao = v + mat;

    dim3 gemm_grid(32, 32);
    gemm_bias_nt<<<gemm_grid, 256, 0, stream>>>(x, wq, bq, q);
    gemm_bias_nt<<<gemm_grid, 256, 0, stream>>>(x, wk, bk, k);
    gemm_bias_nt<<<gemm_grid, 256, 0, stream>>>(x, wv, bv, v);

    rope_kernel<<<dim3((SEQ * CDIM / 2) / 256, 2), 256, 0, stream>>>(q, k, cosT, sinT);

    flash_attn<<<dim3(SEQ / 64, NHEAD), 256, 0, stream>>>(q, k, v, ao);

    gemm_bias_nt<<<gemm_grid, 256, 0, stream>>>(ao, wp, bp, out);
}

// Round 2
// 405.658 us; speedup vs baseline: 5.9131x; 5.9131x over previous
//
#include <hip/hip_runtime.h>
#include <math.h>

typedef __attribute__((ext_vector_type(8))) short  bf16x8;
typedef __attribute__((ext_vector_type(4))) float  f32x4;
typedef __attribute__((ext_vector_type(8))) ushort u16x8;

#define SEQ   2048
#define CDIM  2048
#define NHEAD 16
#define DHEAD 128
#define SCALE 0.02209708691207961f
#define LOG2E 1.4426950408889634f

__device__ __forceinline__ ushort f2bf(float f) {
    uint u = __float_as_uint(f);
    u += 0x7FFFu + ((u >> 16) & 1u);
    return (ushort)(u >> 16);
}
__device__ __forceinline__ float bf2f(ushort h) {
    return __uint_as_float(((uint)h) << 16);
}

#define GLOAD16(gsrc, ldst)                                                  \
    __builtin_amdgcn_global_load_lds(                                        \
        (const __attribute__((address_space(1))) void*)(gsrc),               \
        (__attribute__((address_space(3))) void*)(ldst), 16, 0, 0)

// ---------------------------------------------------------------- f32 -> bf16
__global__ __launch_bounds__(256) void f2bf_kernel(const float* __restrict__ src,
                                                   ushort* __restrict__ dst, int n8)
{
    const int i = blockIdx.x * 256 + threadIdx.x;
    if (i >= n8) return;
    const float4 a = ((const float4*)src)[i * 2];
    const float4 b = ((const float4*)src)[i * 2 + 1];
    u16x8 o;
    o[0] = f2bf(a.x); o[1] = f2bf(a.y); o[2] = f2bf(a.z); o[3] = f2bf(a.w);
    o[4] = f2bf(b.x); o[5] = f2bf(b.y); o[6] = f2bf(b.z); o[7] = f2bf(b.w);
    *(u16x8*)&dst[(size_t)i * 8] = o;
}

// ------------------------------------------------------- bf16 MFMA NT GEMM
// C[m,n] = sum_k A[m,k]*B[n,k] + bias[n]; A,B bf16 row-major [2048][2048]
template <bool OUT_BF16>
__global__ __launch_bounds__(256) void gemm_nt_mfma(const ushort* __restrict__ A,
                                                    const ushort* __restrict__ B,
                                                    const float* __restrict__ bias,
                                                    void* __restrict__ outp)
{
    __shared__ ushort As[128 * 32];
    __shared__ ushort Bs[128 * 32];
    const int tid  = threadIdx.x;
    const int lane = tid & 63, wid = tid >> 6;
    const int wr = wid >> 1, wc = wid & 1;
    const int l4 = lane >> 4, l15 = lane & 15;
    const int m0 = blockIdx.y * 128, n0 = blockIdx.x * 128;

    f32x4 acc[4][4];
    #pragma unroll
    for (int i = 0; i < 4; ++i)
        #pragma unroll
        for (int j = 0; j < 4; ++j) acc[i][j] = 0.f;

    const int srow = wid * 32 + (lane >> 2);
    const int scol = (lane & 3) * 8;

    for (int k0 = 0; k0 < CDIM; k0 += 32) {
        __syncthreads();
        GLOAD16(&A[(size_t)(m0 + srow)      * CDIM + k0 + scol], (char*)As + wid * 2048);
        GLOAD16(&A[(size_t)(m0 + srow + 16) * CDIM + k0 + scol], (char*)As + wid * 2048 + 1024);
        GLOAD16(&B[(size_t)(n0 + srow)      * CDIM + k0 + scol], (char*)Bs + wid * 2048);
        GLOAD16(&B[(size_t)(n0 + srow + 16) * CDIM + k0 + scol], (char*)Bs + wid * 2048 + 1024);
        __syncthreads();

        bf16x8 af[4], bfr[4];
        #pragma unroll
        for (int f = 0; f < 4; ++f) {
            af[f]  = *(const bf16x8*)&As[(wr * 64 + f * 16 + l15) * 32 + l4 * 8];
            bfr[f] = *(const bf16x8*)&Bs[(wc * 64 + f * 16 + l15) * 32 + l4 * 8];
        }
        #pragma unroll
        for (int i = 0; i < 4; ++i)
            #pragma unroll
            for (int j = 0; j < 4; ++j)
                acc[i][j] = __builtin_amdgcn_mfma_f32_16x16x32_bf16(af[i], bfr[j], acc[i][j], 0, 0, 0);
    }

    float bn[4];
    #pragma unroll
    for (int j = 0; j < 4; ++j) bn[j] = bias[n0 + wc * 64 + j * 16 + l15];

    #pragma unroll
    for (int i = 0; i < 4; ++i) {
        #pragma unroll
        for (int j = 0; j < 4; ++j) {
            const int n = n0 + wc * 64 + j * 16 + l15;
            #pragma unroll
            for (int r = 0; r < 4; ++r) {
                const int m = m0 + wr * 64 + i * 16 + l4 * 4 + r;
                const float v = acc[i][j][r] + bn[j];
                if (OUT_BF16) ((ushort*)outp)[(size_t)m * CDIM + n] = f2bf(v);
                else          ((float*)outp)[(size_t)m * CDIM + n] = v;
            }
        }
    }
}

// ---------------------------------------------------------------- RoPE (bf16)
__global__ __launch_bounds__(256) void rope_bf16(ushort* __restrict__ q, ushort* __restrict__ k,
                                                 const float* __restrict__ cosT,
                                                 const float* __restrict__ sinT)
{
    const int idx = blockIdx.x * 256 + threadIdx.x;
    ushort* buf = blockIdx.y ? k : q;
    const int base = idx * 8;
    const int t   = base >> 11;
    const int fi0 = (base & 127) >> 1;
    const float4 c4 = *(const float4*)&cosT[t * 64 + fi0];
    const float4 s4 = *(const float4*)&sinT[t * 64 + fi0];
    const float c[4] = {c4.x, c4.y, c4.z, c4.w};
    const float s[4] = {s4.x, s4.y, s4.z, s4.w};
    u16x8 v = *(const u16x8*)&buf[base];
    u16x8 o;
    #pragma unroll
    for (int p = 0; p < 4; ++p) {
        const float r  = bf2f(v[2 * p]);
        const float im = bf2f(v[2 * p + 1]);
        o[2 * p]     = f2bf(r * c[p] - im * s[p]);
        o[2 * p + 1] = f2bf(r * s[p] + im * c[p]);
    }
    *(u16x8*)&buf[base] = o;
}

// ------------------------------------------------------ MFMA flash attention
// grid (32 q-tiles, 16 heads), 256 threads = 4 waves (2x2).
__global__ __launch_bounds__(256) void flash_attn_mfma(const ushort* __restrict__ qb,
                                                       const ushort* __restrict__ kb,
                                                       const ushort* __restrict__ vb,
                                                       ushort* __restrict__ ao)
{
    __shared__ ushort Ks[64 * 136];   // padded: row stride 272 B
    __shared__ ushort Vt[128 * 72];   // transposed V, XOR-swizzled, stride 144 B
    __shared__ float  S_lds[64 * 68];
    __shared__ ushort Ps[64 * 72];
    __shared__ float  rowM[64], rowL[64], rowF[64];

    const int tid  = threadIdx.x;
    const int lane = tid & 63, wid = tid >> 6;
    const int wr = wid >> 1, wc = wid & 1;
    const int l4 = lane >> 4, l15 = lane & 15;
    const int h = blockIdx.y, qt = blockIdx.x;
    const int q0 = qt * 64;

    if (tid < 64) { rowM[tid] = -INFINITY; rowL[tid] = 0.f; }

    // Q fragments in registers, reused across all K-tiles
    bf16x8 qf[2][4];
    #pragma unroll
    for (int fm = 0; fm < 2; ++fm)
        #pragma unroll
        for (int ks = 0; ks < 4; ++ks) {
            const int row = q0 + wr * 32 + fm * 16 + l15;
            const int col = h * DHEAD + ks * 32 + l4 * 8;
            qf[fm][ks] = *(const bf16x8*)&qb[(size_t)row * CDIM + col];
        }

    f32x4 acc_o[2][4];
    #pragma unroll
    for (int fm = 0; fm < 2; ++fm)
        #pragma unroll
        for (int fn = 0; fn < 4; ++fn) acc_o[fm][fn] = 0.f;

    for (int kt = 0; kt <= qt; ++kt) {
        __syncthreads();   // previous PV done before overwriting LDS

        // ---- stage K tile (64x128, padded rows)
        #pragma unroll
        for (int i2 = 0; i2 < 4; ++i2) {
            const int r  = (tid >> 4) + i2 * 16;
            const int c8 = (tid & 15) * 8;
            *(u16x8*)&Ks[r * 136 + c8] =
                *(const u16x8*)&kb[(size_t)(kt * 64 + r) * CDIM + h * DHEAD + c8];
        }
        // ---- stage V transposed with XOR swizzle
        #pragma unroll
        for (int i2 = 0; i2 < 4; ++i2) {
            const int kv = (tid >> 4) + i2 * 16;
            const int d0 = (tid & 15) * 8;
            u16x8 vv = *(const u16x8*)&vb[(size_t)(kt * 64 + kv) * CDIM + h * DHEAD + d0];
            #pragma unroll
            for (int e = 0; e < 8; ++e) {
                const int d = d0 + e;
                const uint byteoff = (uint)(d * 144 + kv * 2) ^ ((((uint)d >> 3) & 7u) << 4);
                *(ushort*)((char*)Vt + byteoff) = vv[e];
            }
        }
        __syncthreads();

        // ---- S = Q K^T  (each wave: 32x32 of the 64x64 tile)
        f32x4 sacc[2][2];
        #pragma unroll
        for (int fm = 0; fm < 2; ++fm)
            #pragma unroll
            for (int fn = 0; fn < 2; ++fn) sacc[fm][fn] = 0.f;
        #pragma unroll
        for (int ks = 0; ks < 4; ++ks) {
            bf16x8 kf[2];
            #pragma unroll
            for (int fn = 0; fn < 2; ++fn)
                kf[fn] = *(const bf16x8*)&Ks[(wc * 32 + fn * 16 + l15) * 136 + ks * 32 + l4 * 8];
            #pragma unroll
            for (int fm = 0; fm < 2; ++fm)
                #pragma unroll
                for (int fn = 0; fn < 2; ++fn)
                    sacc[fm][fn] = __builtin_amdgcn_mfma_f32_16x16x32_bf16(qf[fm][ks], kf[fn], sacc[fm][fn], 0, 0, 0);
        }
        #pragma unroll
        for (int fm = 0; fm < 2; ++fm)
            #pragma unroll
            for (int fn = 0; fn < 2; ++fn)
                #pragma unroll
                for (int r = 0; r < 4; ++r) {
                    const int srow = wr * 32 + fm * 16 + l4 * 4 + r;
                    const int scol = wc * 32 + fn * 16 + l15;
                    float sv = sacc[fm][fn][r] * SCALE;
                    if (kt == qt && scol > srow) sv = -INFINITY;
                    S_lds[srow * 68 + scol] = sv;
                }
        __syncthreads();

        // ---- online softmax: 4 lanes per row
        {
            const int srow = tid >> 2;
            const int c0   = (tid & 3) * 16;
            float vals[16];
            #pragma unroll
            for (int c = 0; c < 16; ++c) vals[c] = S_lds[srow * 68 + c0 + c];
            float mt = vals[0];
            #pragma unroll
            for (int c = 1; c < 16; ++c) mt = fmaxf(mt, vals[c]);
            mt = fmaxf(mt, __shfl_xor(mt, 1));
            mt = fmaxf(mt, __shfl_xor(mt, 2));
            const float mold = rowM[srow];
            const float mnew = fmaxf(mold, mt);
            float sum = 0.f;
            ushort pb[16];
            #pragma unroll
            for (int c = 0; c < 16; ++c) {
                const float p = exp2f((vals[c] - mnew) * LOG2E);
                sum += p;
                pb[c] = f2bf(p);
            }
            sum += __shfl_xor(sum, 1);
            sum += __shfl_xor(sum, 2);
            u16x8 w0, w1;
            #pragma unroll
            for (int c = 0; c < 8; ++c) { w0[c] = pb[c]; w1[c] = pb[c + 8]; }
            *(u16x8*)&Ps[srow * 72 + c0]     = w0;
            *(u16x8*)&Ps[srow * 72 + c0 + 8] = w1;
            if ((tid & 3) == 0) {
                const float fac = exp2f((mold - mnew) * LOG2E);
                rowF[srow] = fac;
                rowL[srow] = rowL[srow] * fac + sum;
                rowM[srow] = mnew;
            }
        }
        __syncthreads();

        // ---- rescale O, then O += P V
        float frv[2][4];
        #pragma unroll
        for (int fm = 0; fm < 2; ++fm)
            #pragma unroll
            for (int r = 0; r < 4; ++r)
                frv[fm][r] = rowF[wr * 32 + fm * 16 + l4 * 4 + r];
        #pragma unroll
        for (int fm = 0; fm < 2; ++fm)
            #pragma unroll
            for (int fn = 0; fn < 4; ++fn)
                #pragma unroll
                for (int r = 0; r < 4; ++r) acc_o[fm][fn][r] *= frv[fm][r];

        #pragma unroll
        for (int ks = 0; ks < 2; ++ks) {
            bf16x8 pa[2];
            #pragma unroll
            for (int fm = 0; fm < 2; ++fm)
                pa[fm] = *(const bf16x8*)&Ps[(wr * 32 + fm * 16 + l15) * 72 + ks * 32 + l4 * 8];
            #pragma unroll
            for (int fn = 0; fn < 4; ++fn) {
                const int n = wc * 64 + fn * 16 + l15;
                const uint byteoff = (uint)(n * 144 + ks * 64 + l4 * 16) ^ ((((uint)n >> 3) & 7u) << 4);
                bf16x8 vf = *(const bf16x8*)((const char*)Vt + byteoff);
                #pragma unroll
                for (int fm = 0; fm < 2; ++fm)
                    acc_o[fm][fn] = __builtin_amdgcn_mfma_f32_16x16x32_bf16(pa[fm], vf, acc_o[fm][fn], 0, 0, 0);
            }
        }
    }

    // ---- epilogue: O /= rowL, store bf16
    #pragma unroll
    for (int fm = 0; fm < 2; ++fm) {
        #pragma unroll
        for (int r = 0; r < 4; ++r) {
            const int lrow = wr * 32 + fm * 16 + l4 * 4 + r;
            const float invl = 1.f / rowL[lrow];
            #pragma unroll
            for (int fn = 0; fn < 4; ++fn) {
                const int gcol = h * DHEAD + wc * 64 + fn * 16 + l15;
                ao[(size_t)(q0 + lrow) * CDIM + gcol] = f2bf(acc_o[fm][fn][r] * invl);
            }
        }
    }
}

extern "C" void kernel_launch(void* const* d_in, const int* in_sizes, int n_in,
                              void* d_out, int out_size, void* d_ws, size_t ws_size,
                              hipStream_t stream) {
    const float* x    = (const float*)d_in[0];
    const float* wq   = (const float*)d_in[1];
    const float* bq   = (const float*)d_in[2];
    const float* wk   = (const float*)d_in[3];
    const float* bk   = (const float*)d_in[4];
    const float* wv   = (const float*)d_in[5];
    const float* bv   = (const float*)d_in[6];
    const float* wp   = (const float*)d_in[7];
    const float* bp   = (const float*)d_in[8];
    const float* cosT = (const float*)d_in[9];
    const float* sinT = (const float*)d_in[10];
    float* out = (float*)d_out;

    const size_t mat = (size_t)SEQ * CDIM;   // 4M elements
    ushort* xb  = (ushort*)d_ws;
    ushort* wb  = xb  + mat;
    ushort* qbb = wb  + mat;
    ushort* kbb = qbb + mat;
    ushort* vbb = kbb + mat;
    ushort* aob = vbb + mat;

    const int n8 = (int)(mat / 8);
    const dim3 cgrid(n8 / 256);
    const dim3 ggrid(16, 16);

    f2bf_kernel<<<cgrid, 256, 0, stream>>>(x, xb, n8);

    f2bf_kernel<<<cgrid, 256, 0, stream>>>(wq, wb, n8);
    gemm_nt_mfma<true><<<ggrid, 256, 0, stream>>>(xb, wb, bq, (void*)qbb);
    f2bf_kernel<<<cgrid, 256, 0, stream>>>(wk, wb, n8);
    gemm_nt_mfma<true><<<ggrid, 256, 0, stream>>>(xb, wb, bk, (void*)kbb);
    f2bf_kernel<<<cgrid, 256, 0, stream>>>(wv, wb, n8);
    gemm_nt_mfma<true><<<ggrid, 256, 0, stream>>>(xb, wb, bv, (void*)vbb);

    rope_bf16<<<dim3(SEQ * CDIM / 8 / 256, 2), 256, 0, stream>>>(qbb, kbb, cosT, sinT);

    flash_attn_mfma<<<dim3(SEQ / 64, NHEAD), 256, 0, stream>>>(qbb, kbb, vbb, aob);

    f2bf_kernel<<<cgrid, 256, 0, stream>>>(wp, wb, n8);
    gemm_nt_mfma<false><<<ggrid, 256, 0, stream>>>(aob, wb, bp, d_out);

    (void)out; (void)in_sizes; (void)n_in; (void)out_size; (void)ws_size;
}

// Round 3
// 351.467 us; speedup vs baseline: 6.8248x; 1.1542x over previous
//
#include <hip/hip_runtime.h>
#include <math.h>

typedef __attribute__((ext_vector_type(8))) short  bf16x8;
typedef __attribute__((ext_vector_type(4))) float  f32x4;
typedef __attribute__((ext_vector_type(8))) ushort u16x8;
typedef __attribute__((ext_vector_type(4))) ushort u16x4;

#define SEQ   2048
#define CDIM  2048
#define NHEAD 16
#define DHEAD 128
#define SCALE 0.02209708691207961f
#define LOG2E 1.4426950408889634f

__device__ __forceinline__ ushort f2bf(float f) {
    uint u = __float_as_uint(f);
    u += 0x7FFFu + ((u >> 16) & 1u);
    return (ushort)(u >> 16);
}
__device__ __forceinline__ float bf2f(ushort h) {
    return __uint_as_float(((uint)h) << 16);
}

#define GLOAD16(gsrc, ldst)                                                  \
    __builtin_amdgcn_global_load_lds(                                        \
        (const __attribute__((address_space(1))) void*)(gsrc),               \
        (__attribute__((address_space(3))) void*)(ldst), 16, 0, 0)

// ---------------------------------------------------------------- f32 -> bf16
__global__ __launch_bounds__(256) void f2bf_kernel(const float* __restrict__ src,
                                                   ushort* __restrict__ dst, int n8)
{
    const int i = blockIdx.x * 256 + threadIdx.x;
    if (i >= n8) return;
    const float4 a = ((const float4*)src)[i * 2];
    const float4 b = ((const float4*)src)[i * 2 + 1];
    u16x8 o;
    o[0] = f2bf(a.x); o[1] = f2bf(a.y); o[2] = f2bf(a.z); o[3] = f2bf(a.w);
    o[4] = f2bf(b.x); o[5] = f2bf(b.y); o[6] = f2bf(b.z); o[7] = f2bf(b.w);
    *(u16x8*)&dst[(size_t)i * 8] = o;
}

// batched: converts 3 weight matrices (blockIdx.y selects)
__global__ __launch_bounds__(256) void f2bf3_kernel(const float* __restrict__ s0,
                                                    const float* __restrict__ s1,
                                                    const float* __restrict__ s2,
                                                    ushort* __restrict__ d0,
                                                    ushort* __restrict__ d1,
                                                    ushort* __restrict__ d2)
{
    const int z = blockIdx.y;
    const float* src = z == 0 ? s0 : z == 1 ? s1 : s2;
    ushort*      dst = z == 0 ? d0 : z == 1 ? d1 : d2;
    const int i = blockIdx.x * 256 + threadIdx.x;
    const float4 a = ((const float4*)src)[i * 2];
    const float4 b = ((const float4*)src)[i * 2 + 1];
    u16x8 o;
    o[0] = f2bf(a.x); o[1] = f2bf(a.y); o[2] = f2bf(a.z); o[3] = f2bf(a.w);
    o[4] = f2bf(b.x); o[5] = f2bf(b.y); o[6] = f2bf(b.z); o[7] = f2bf(b.w);
    *(u16x8*)&dst[(size_t)i * 8] = o;
}

// ------------------------------------------------------- bf16 MFMA NT GEMM
// C[m,n] = sum_k A[m,k]*B[n,k] + bias[n]; out fp32 (final projection)
__global__ __launch_bounds__(256) void gemm_nt_mfma_f32(const ushort* __restrict__ A,
                                                        const ushort* __restrict__ B,
                                                        const float* __restrict__ bias,
                                                        float* __restrict__ outp)
{
    __shared__ ushort As[128 * 32];
    __shared__ ushort Bs[128 * 32];
    const int tid  = threadIdx.x;
    const int lane = tid & 63, wid = tid >> 6;
    const int wr = wid >> 1, wc = wid & 1;
    const int l4 = lane >> 4, l15 = lane & 15;
    const int m0 = blockIdx.y * 128, n0 = blockIdx.x * 128;

    f32x4 acc[4][4];
    #pragma unroll
    for (int i = 0; i < 4; ++i)
        #pragma unroll
        for (int j = 0; j < 4; ++j) acc[i][j] = 0.f;

    const int srow = wid * 32 + (lane >> 2);
    const int scol = (lane & 3) * 8;

    for (int k0 = 0; k0 < CDIM; k0 += 32) {
        __syncthreads();
        GLOAD16(&A[(size_t)(m0 + srow)      * CDIM + k0 + scol], (char*)As + wid * 2048);
        GLOAD16(&A[(size_t)(m0 + srow + 16) * CDIM + k0 + scol], (char*)As + wid * 2048 + 1024);
        GLOAD16(&B[(size_t)(n0 + srow)      * CDIM + k0 + scol], (char*)Bs + wid * 2048);
        GLOAD16(&B[(size_t)(n0 + srow + 16) * CDIM + k0 + scol], (char*)Bs + wid * 2048 + 1024);
        __syncthreads();

        bf16x8 af[4], bfr[4];
        #pragma unroll
        for (int f = 0; f < 4; ++f) {
            af[f]  = *(const bf16x8*)&As[(wr * 64 + f * 16 + l15) * 32 + l4 * 8];
            bfr[f] = *(const bf16x8*)&Bs[(wc * 64 + f * 16 + l15) * 32 + l4 * 8];
        }
        #pragma unroll
        for (int i = 0; i < 4; ++i)
            #pragma unroll
            for (int j = 0; j < 4; ++j)
                acc[i][j] = __builtin_amdgcn_mfma_f32_16x16x32_bf16(af[i], bfr[j], acc[i][j], 0, 0, 0);
    }

    float bn[4];
    #pragma unroll
    for (int j = 0; j < 4; ++j) bn[j] = bias[n0 + wc * 64 + j * 16 + l15];

    #pragma unroll
    for (int i = 0; i < 4; ++i)
        #pragma unroll
        for (int j = 0; j < 4; ++j) {
            const int n = n0 + wc * 64 + j * 16 + l15;
            #pragma unroll
            for (int r = 0; r < 4; ++r) {
                const int m = m0 + wr * 64 + i * 16 + l4 * 4 + r;
                outp[(size_t)m * CDIM + n] = acc[i][j][r] + bn[j];
            }
        }
}

// Fused QKV GEMM: blockIdx.z selects weight/bias/output.
// z==0 -> q (bf16 row-major), z==1 -> k (bf16 row-major),
// z==2 -> vT (bf16 TRANSPOSED: vT[n][m], leading dim SEQ).
__global__ __launch_bounds__(256) void gemm_qkv(const ushort* __restrict__ A,
                                                const ushort* __restrict__ W0,
                                                const ushort* __restrict__ W1,
                                                const ushort* __restrict__ W2,
                                                const float* __restrict__ b0,
                                                const float* __restrict__ b1,
                                                const float* __restrict__ b2,
                                                ushort* __restrict__ o0,
                                                ushort* __restrict__ o1,
                                                ushort* __restrict__ o2)
{
    __shared__ ushort As[128 * 32];
    __shared__ ushort Bs[128 * 32];
    const int z = blockIdx.z;
    const ushort* B    = z == 0 ? W0 : z == 1 ? W1 : W2;
    const float*  bias = z == 0 ? b0 : z == 1 ? b1 : b2;

    const int tid  = threadIdx.x;
    const int lane = tid & 63, wid = tid >> 6;
    const int wr = wid >> 1, wc = wid & 1;
    const int l4 = lane >> 4, l15 = lane & 15;
    const int m0 = blockIdx.y * 128, n0 = blockIdx.x * 128;

    f32x4 acc[4][4];
    #pragma unroll
    for (int i = 0; i < 4; ++i)
        #pragma unroll
        for (int j = 0; j < 4; ++j) acc[i][j] = 0.f;

    const int srow = wid * 32 + (lane >> 2);
    const int scol = (lane & 3) * 8;

    for (int k0 = 0; k0 < CDIM; k0 += 32) {
        __syncthreads();
        GLOAD16(&A[(size_t)(m0 + srow)      * CDIM + k0 + scol], (char*)As + wid * 2048);
        GLOAD16(&A[(size_t)(m0 + srow + 16) * CDIM + k0 + scol], (char*)As + wid * 2048 + 1024);
        GLOAD16(&B[(size_t)(n0 + srow)      * CDIM + k0 + scol], (char*)Bs + wid * 2048);
        GLOAD16(&B[(size_t)(n0 + srow + 16) * CDIM + k0 + scol], (char*)Bs + wid * 2048 + 1024);
        __syncthreads();

        bf16x8 af[4], bfr[4];
        #pragma unroll
        for (int f = 0; f < 4; ++f) {
            af[f]  = *(const bf16x8*)&As[(wr * 64 + f * 16 + l15) * 32 + l4 * 8];
            bfr[f] = *(const bf16x8*)&Bs[(wc * 64 + f * 16 + l15) * 32 + l4 * 8];
        }
        #pragma unroll
        for (int i = 0; i < 4; ++i)
            #pragma unroll
            for (int j = 0; j < 4; ++j)
                acc[i][j] = __builtin_amdgcn_mfma_f32_16x16x32_bf16(af[i], bfr[j], acc[i][j], 0, 0, 0);
    }

    float bn[4];
    #pragma unroll
    for (int j = 0; j < 4; ++j) bn[j] = bias[n0 + wc * 64 + j * 16 + l15];

    if (z == 2) {
        // transposed write: vT[n][m], 4 consecutive m per lane -> 8B stores
        #pragma unroll
        for (int i = 0; i < 4; ++i)
            #pragma unroll
            for (int j = 0; j < 4; ++j) {
                const int n = n0 + wc * 64 + j * 16 + l15;
                const int mb = m0 + wr * 64 + i * 16 + l4 * 4;
                u16x4 pk;
                #pragma unroll
                for (int r = 0; r < 4; ++r) pk[r] = f2bf(acc[i][j][r] + bn[j]);
                *(u16x4*)&o2[(size_t)n * SEQ + mb] = pk;
            }
    } else {
        ushort* outp = z == 0 ? o0 : o1;
        #pragma unroll
        for (int i = 0; i < 4; ++i)
            #pragma unroll
            for (int j = 0; j < 4; ++j) {
                const int n = n0 + wc * 64 + j * 16 + l15;
                #pragma unroll
                for (int r = 0; r < 4; ++r) {
                    const int m = m0 + wr * 64 + i * 16 + l4 * 4 + r;
                    outp[(size_t)m * CDIM + n] = f2bf(acc[i][j][r] + bn[j]);
                }
            }
    }
}

// ---------------------------------------------------------------- RoPE (bf16)
__global__ __launch_bounds__(256) void rope_bf16(ushort* __restrict__ q, ushort* __restrict__ k,
                                                 const float* __restrict__ cosT,
                                                 const float* __restrict__ sinT)
{
    const int idx = blockIdx.x * 256 + threadIdx.x;
    ushort* buf = blockIdx.y ? k : q;
    const int base = idx * 8;
    const int t   = base >> 11;
    const int fi0 = (base & 127) >> 1;
    const float4 c4 = *(const float4*)&cosT[t * 64 + fi0];
    const float4 s4 = *(const float4*)&sinT[t * 64 + fi0];
    const float c[4] = {c4.x, c4.y, c4.z, c4.w};
    const float s[4] = {s4.x, s4.y, s4.z, s4.w};
    u16x8 v = *(const u16x8*)&buf[base];
    u16x8 o;
    #pragma unroll
    for (int p = 0; p < 4; ++p) {
        const float r  = bf2f(v[2 * p]);
        const float im = bf2f(v[2 * p + 1]);
        o[2 * p]     = f2bf(r * c[p] - im * s[p]);
        o[2 * p + 1] = f2bf(r * s[p] + im * c[p]);
    }
    *(u16x8*)&buf[base] = o;
}

// ------------------------------------------------------ MFMA flash attention
// grid (32 q-tiles reversed, 16 heads), 256 threads = 4 waves (2x2).
// V comes in pre-transposed: vT[d_global][t].
__global__ __launch_bounds__(256) void flash_attn_mfma(const ushort* __restrict__ qb,
                                                       const ushort* __restrict__ kb,
                                                       const ushort* __restrict__ vT,
                                                       ushort* __restrict__ ao)
{
    __shared__ ushort Ks[64 * 136];    // row stride 272 B
    __shared__ ushort VTs[128 * 72];   // [d][kv], row stride 144 B
    __shared__ float  S_lds[64 * 68];
    __shared__ ushort Ps[64 * 72];
    __shared__ float  rowM[64], rowL[64], rowF[64];

    const int tid  = threadIdx.x;
    const int lane = tid & 63, wid = tid >> 6;
    const int wr = wid >> 1, wc = wid & 1;
    const int l4 = lane >> 4, l15 = lane & 15;
    const int h = blockIdx.y;
    const int qt = gridDim.x - 1 - blockIdx.x;   // longest blocks dispatch first
    const int q0 = qt * 64;

    if (tid < 64) { rowM[tid] = -INFINITY; rowL[tid] = 0.f; }

    // Q fragments in registers, reused across all K-tiles
    bf16x8 qf[2][4];
    #pragma unroll
    for (int fm = 0; fm < 2; ++fm)
        #pragma unroll
        for (int ks = 0; ks < 4; ++ks) {
            const int row = q0 + wr * 32 + fm * 16 + l15;
            const int col = h * DHEAD + ks * 32 + l4 * 8;
            qf[fm][ks] = *(const bf16x8*)&qb[(size_t)row * CDIM + col];
        }

    f32x4 acc_o[2][4];
    #pragma unroll
    for (int fm = 0; fm < 2; ++fm)
        #pragma unroll
        for (int fn = 0; fn < 4; ++fn) acc_o[fm][fn] = 0.f;

    for (int kt = 0; kt <= qt; ++kt) {
        __syncthreads();   // previous PV done before overwriting LDS

        // ---- stage K tile (64 rows x 128 d), vectorized
        #pragma unroll
        for (int i2 = 0; i2 < 4; ++i2) {
            const int r  = (tid >> 4) + i2 * 16;
            const int c8 = (tid & 15) * 8;
            *(u16x8*)&Ks[r * 136 + c8] =
                *(const u16x8*)&kb[(size_t)(kt * 64 + r) * CDIM + h * DHEAD + c8];
        }
        // ---- stage V^T tile (128 d x 64 kv), vectorized
        #pragma unroll
        for (int i2 = 0; i2 < 4; ++i2) {
            const int r  = (tid >> 3) + i2 * 32;          // d: 0..127
            const int c8 = (tid & 7) * 8;                 // kv: 0..56
            *(u16x8*)&VTs[r * 72 + c8] =
                *(const u16x8*)&vT[(size_t)(h * DHEAD + r) * SEQ + kt * 64 + c8];
        }
        __syncthreads();

        // ---- S = Q K^T  (each wave: 32x32 of the 64x64 tile)
        f32x4 sacc[2][2];
        #pragma unroll
        for (int fm = 0; fm < 2; ++fm)
            #pragma unroll
            for (int fn = 0; fn < 2; ++fn) sacc[fm][fn] = 0.f;
        #pragma unroll
        for (int ks = 0; ks < 4; ++ks) {
            bf16x8 kf[2];
            #pragma unroll
            for (int fn = 0; fn < 2; ++fn)
                kf[fn] = *(const bf16x8*)&Ks[(wc * 32 + fn * 16 + l15) * 136 + ks * 32 + l4 * 8];
            #pragma unroll
            for (int fm = 0; fm < 2; ++fm)
                #pragma unroll
                for (int fn = 0; fn < 2; ++fn)
                    sacc[fm][fn] = __builtin_amdgcn_mfma_f32_16x16x32_bf16(qf[fm][ks], kf[fn], sacc[fm][fn], 0, 0, 0);
        }
        #pragma unroll
        for (int fm = 0; fm < 2; ++fm)
            #pragma unroll
            for (int fn = 0; fn < 2; ++fn)
                #pragma unroll
                for (int r = 0; r < 4; ++r) {
                    const int srow = wr * 32 + fm * 16 + l4 * 4 + r;
                    const int scol = wc * 32 + fn * 16 + l15;
                    float sv = sacc[fm][fn][r] * SCALE;
                    if (kt == qt && scol > srow) sv = -INFINITY;
                    S_lds[srow * 68 + scol] = sv;
                }
        __syncthreads();

        // ---- online softmax: 4 lanes per row
        {
            const int srow = tid >> 2;
            const int c0   = (tid & 3) * 16;
            float vals[16];
            #pragma unroll
            for (int c = 0; c < 16; ++c) vals[c] = S_lds[srow * 68 + c0 + c];
            float mt = vals[0];
            #pragma unroll
            for (int c = 1; c < 16; ++c) mt = fmaxf(mt, vals[c]);
            mt = fmaxf(mt, __shfl_xor(mt, 1));
            mt = fmaxf(mt, __shfl_xor(mt, 2));
            const float mold = rowM[srow];
            const float mnew = fmaxf(mold, mt);
            float sum = 0.f;
            ushort pb[16];
            #pragma unroll
            for (int c = 0; c < 16; ++c) {
                const float p = exp2f((vals[c] - mnew) * LOG2E);
                sum += p;
                pb[c] = f2bf(p);
            }
            sum += __shfl_xor(sum, 1);
            sum += __shfl_xor(sum, 2);
            u16x8 w0, w1;
            #pragma unroll
            for (int c = 0; c < 8; ++c) { w0[c] = pb[c]; w1[c] = pb[c + 8]; }
            *(u16x8*)&Ps[srow * 72 + c0]     = w0;
            *(u16x8*)&Ps[srow * 72 + c0 + 8] = w1;
            if ((tid & 3) == 0) {
                const float fac = exp2f((mold - mnew) * LOG2E);
                rowF[srow] = fac;
                rowL[srow] = rowL[srow] * fac + sum;
                rowM[srow] = mnew;
            }
        }
        __syncthreads();

        // ---- rescale O, then O += P V
        float frv[2][4];
        #pragma unroll
        for (int fm = 0; fm < 2; ++fm)
            #pragma unroll
            for (int r = 0; r < 4; ++r)
                frv[fm][r] = rowF[wr * 32 + fm * 16 + l4 * 4 + r];
        #pragma unroll
        for (int fm = 0; fm < 2; ++fm)
            #pragma unroll
            for (int fn = 0; fn < 4; ++fn)
                #pragma unroll
                for (int r = 0; r < 4; ++r) acc_o[fm][fn][r] *= frv[fm][r];

        #pragma unroll
        for (int ks = 0; ks < 2; ++ks) {
            bf16x8 pa[2];
            #pragma unroll
            for (int fm = 0; fm < 2; ++fm)
                pa[fm] = *(const bf16x8*)&Ps[(wr * 32 + fm * 16 + l15) * 72 + ks * 32 + l4 * 8];
            #pragma unroll
            for (int fn = 0; fn < 4; ++fn) {
                bf16x8 vf = *(const bf16x8*)&VTs[(wc * 64 + fn * 16 + l15) * 72 + ks * 32 + l4 * 8];
                #pragma unroll
                for (int fm = 0; fm < 2; ++fm)
                    acc_o[fm][fn] = __builtin_amdgcn_mfma_f32_16x16x32_bf16(pa[fm], vf, acc_o[fm][fn], 0, 0, 0);
            }
        }
    }

    // ---- epilogue: O /= rowL, store bf16
    #pragma unroll
    for (int fm = 0; fm < 2; ++fm)
        #pragma unroll
        for (int r = 0; r < 4; ++r) {
            const int lrow = wr * 32 + fm * 16 + l4 * 4 + r;
            const float invl = 1.f / rowL[lrow];
            #pragma unroll
            for (int fn = 0; fn < 4; ++fn) {
                const int gcol = h * DHEAD + wc * 64 + fn * 16 + l15;
                ao[(size_t)(q0 + lrow) * CDIM + gcol] = f2bf(acc_o[fm][fn][r] * invl);
            }
        }
}

extern "C" void kernel_launch(void* const* d_in, const int* in_sizes, int n_in,
                              void* d_out, int out_size, void* d_ws, size_t ws_size,
                              hipStream_t stream) {
    const float* x    = (const float*)d_in[0];
    const float* wq   = (const float*)d_in[1];
    const float* bq   = (const float*)d_in[2];
    const float* wk   = (const float*)d_in[3];
    const float* bk   = (const float*)d_in[4];
    const float* wv   = (const float*)d_in[5];
    const float* bv   = (const float*)d_in[6];
    const float* wp   = (const float*)d_in[7];
    const float* bp   = (const float*)d_in[8];
    const float* cosT = (const float*)d_in[9];
    const float* sinT = (const float*)d_in[10];

    const size_t mat = (size_t)SEQ * CDIM;   // 4M elements
    ushort* xb  = (ushort*)d_ws;
    ushort* w0  = xb  + mat;
    ushort* w1  = w0  + mat;
    ushort* w2  = w1  + mat;
    ushort* qbb = w2  + mat;
    ushort* kbb = qbb + mat;
    ushort* vTb = kbb + mat;
    ushort* aob = w0;            // reuse w0 after QKV GEMM

    const int n8 = (int)(mat / 8);
    const dim3 cgrid(n8 / 256);

    f2bf_kernel<<<cgrid, 256, 0, stream>>>(x, xb, n8);
    f2bf3_kernel<<<dim3(n8 / 256, 3), 256, 0, stream>>>(wq, wk, wv, w0, w1, w2);

    gemm_qkv<<<dim3(16, 16, 3), 256, 0, stream>>>(xb, w0, w1, w2, bq, bk, bv,
                                                  qbb, kbb, vTb);

    rope_bf16<<<dim3(SEQ * CDIM / 8 / 256, 2), 256, 0, stream>>>(qbb, kbb, cosT, sinT);

    flash_attn_mfma<<<dim3(SEQ / 64, NHEAD), 256, 0, stream>>>(qbb, kbb, vTb, aob);

    f2bf_kernel<<<cgrid, 256, 0, stream>>>(wp, w1, n8);
    gemm_nt_mfma_f32<<<dim3(16, 16), 256, 0, stream>>>(aob, w1, bp, (float*)d_out);

    (void)in_sizes; (void)n_in; (void)out_size; (void)ws_size;
}

// Round 5
// 344.217 us; speedup vs baseline: 6.9686x; 1.0211x over previous
//
#include <hip/hip_runtime.h>
#include <math.h>

typedef __attribute__((ext_vector_type(8))) short  bf16x8;
typedef __attribute__((ext_vector_type(4))) float  f32x4;
typedef __attribute__((ext_vector_type(8))) ushort u16x8;
typedef __attribute__((ext_vector_type(4))) ushort u16x4;

#define SEQ   2048
#define CDIM  2048
#define NHEAD 16
#define DHEAD 128
#define SCALE 0.02209708691207961f
#define LOG2E 1.4426950408889634f

__device__ __forceinline__ ushort f2bf(float f) {
    uint u = __float_as_uint(f);
    u += 0x7FFFu + ((u >> 16) & 1u);
    return (ushort)(u >> 16);
}
__device__ __forceinline__ float bf2f(ushort h) {
    return __uint_as_float(((uint)h) << 16);
}

#define GLOAD16(gsrc, ldst)                                                  \
    __builtin_amdgcn_global_load_lds(                                        \
        (const __attribute__((address_space(1))) void*)(gsrc),               \
        (__attribute__((address_space(3))) void*)(ldst), 16, 0, 0)

// ------------------------------------------ f32 -> bf16, 5 matrices fused
__global__ __launch_bounds__(256) void f2bf5_kernel(
    const float* __restrict__ s0, const float* __restrict__ s1,
    const float* __restrict__ s2, const float* __restrict__ s3,
    const float* __restrict__ s4,
    ushort* __restrict__ d0, ushort* __restrict__ d1,
    ushort* __restrict__ d2, ushort* __restrict__ d3,
    ushort* __restrict__ d4)
{
    const int z = blockIdx.y;
    const float* src = z == 0 ? s0 : z == 1 ? s1 : z == 2 ? s2 : z == 3 ? s3 : s4;
    ushort*      dst = z == 0 ? d0 : z == 1 ? d1 : z == 2 ? d2 : z == 3 ? d3 : d4;
    const int i = blockIdx.x * 256 + threadIdx.x;
    const float4 a = ((const float4*)src)[i * 2];
    const float4 b = ((const float4*)src)[i * 2 + 1];
    u16x8 o;
    o[0] = f2bf(a.x); o[1] = f2bf(a.y); o[2] = f2bf(a.z); o[3] = f2bf(a.w);
    o[4] = f2bf(b.x); o[5] = f2bf(b.y); o[6] = f2bf(b.z); o[7] = f2bf(b.w);
    *(u16x8*)&dst[(size_t)i * 8] = o;
}

// ------------------------------------------------------- bf16 MFMA NT GEMM
// C[m,n] = sum_k A[m,k]*B[n,k] + bias[n]; out fp32 (final projection)
__global__ __launch_bounds__(256) void gemm_nt_mfma_f32(const ushort* __restrict__ A,
                                                        const ushort* __restrict__ B,
                                                        const float* __restrict__ bias,
                                                        float* __restrict__ outp)
{
    __shared__ ushort As[128 * 32];
    __shared__ ushort Bs[128 * 32];
    const int tid  = threadIdx.x;
    const int lane = tid & 63, wid = tid >> 6;
    const int wr = wid >> 1, wc = wid & 1;
    const int l4 = lane >> 4, l15 = lane & 15;
    const int m0 = blockIdx.y * 128, n0 = blockIdx.x * 128;

    f32x4 acc[4][4];
    #pragma unroll
    for (int i = 0; i < 4; ++i)
        #pragma unroll
        for (int j = 0; j < 4; ++j) acc[i][j] = 0.f;

    const int srow = wid * 32 + (lane >> 2);
    const int scol = (lane & 3) * 8;

    for (int k0 = 0; k0 < CDIM; k0 += 32) {
        __syncthreads();
        GLOAD16(&A[(size_t)(m0 + srow)      * CDIM + k0 + scol], (char*)As + wid * 2048);
        GLOAD16(&A[(size_t)(m0 + srow + 16) * CDIM + k0 + scol], (char*)As + wid * 2048 + 1024);
        GLOAD16(&B[(size_t)(n0 + srow)      * CDIM + k0 + scol], (char*)Bs + wid * 2048);
        GLOAD16(&B[(size_t)(n0 + srow + 16) * CDIM + k0 + scol], (char*)Bs + wid * 2048 + 1024);
        __syncthreads();

        bf16x8 af[4], bfr[4];
        #pragma unroll
        for (int f = 0; f < 4; ++f) {
            af[f]  = *(const bf16x8*)&As[(wr * 64 + f * 16 + l15) * 32 + l4 * 8];
            bfr[f] = *(const bf16x8*)&Bs[(wc * 64 + f * 16 + l15) * 32 + l4 * 8];
        }
        #pragma unroll
        for (int i = 0; i < 4; ++i)
            #pragma unroll
            for (int j = 0; j < 4; ++j)
                acc[i][j] = __builtin_amdgcn_mfma_f32_16x16x32_bf16(af[i], bfr[j], acc[i][j], 0, 0, 0);
    }

    float bn[4];
    #pragma unroll
    for (int j = 0; j < 4; ++j) bn[j] = bias[n0 + wc * 64 + j * 16 + l15];

    #pragma unroll
    for (int i = 0; i < 4; ++i)
        #pragma unroll
        for (int j = 0; j < 4; ++j) {
            const int n = n0 + wc * 64 + j * 16 + l15;
            #pragma unroll
            for (int r = 0; r < 4; ++r) {
                const int m = m0 + wr * 64 + i * 16 + l4 * 4 + r;
                outp[(size_t)m * CDIM + n] = acc[i][j][r] + bn[j];
            }
        }
}

// Fused QKV GEMM + RoPE epilogue (q,k). blockIdx.z selects weight/bias/output.
// z==0 -> q (bf16 row-major, rope), z==1 -> k (bf16 row-major, rope),
// z==2 -> vT (bf16 TRANSPOSED: vT[n][m], leading dim SEQ, no rope).
__global__ __launch_bounds__(256) void gemm_qkv(const ushort* __restrict__ A,
                                                const ushort* __restrict__ W0,
                                                const ushort* __restrict__ W1,
                                                const ushort* __restrict__ W2,
                                                const float* __restrict__ b0,
                                                const float* __restrict__ b1,
                                                const float* __restrict__ b2,
                                                const float* __restrict__ cosT,
                                                const float* __restrict__ sinT,
                                                ushort* __restrict__ o0,
                                                ushort* __restrict__ o1,
                                                ushort* __restrict__ o2)
{
    __shared__ ushort As[128 * 32];
    __shared__ ushort Bs[128 * 32];
    const int z = blockIdx.z;
    const ushort* B    = z == 0 ? W0 : z == 1 ? W1 : W2;
    const float*  bias = z == 0 ? b0 : z == 1 ? b1 : b2;

    const int tid  = threadIdx.x;
    const int lane = tid & 63, wid = tid >> 6;
    const int wr = wid >> 1, wc = wid & 1;
    const int l4 = lane >> 4, l15 = lane & 15;
    const int m0 = blockIdx.y * 128, n0 = blockIdx.x * 128;

    f32x4 acc[4][4];
    #pragma unroll
    for (int i = 0; i < 4; ++i)
        #pragma unroll
        for (int j = 0; j < 4; ++j) acc[i][j] = 0.f;

    const int srow = wid * 32 + (lane >> 2);
    const int scol = (lane & 3) * 8;

    for (int k0 = 0; k0 < CDIM; k0 += 32) {
        __syncthreads();
        GLOAD16(&A[(size_t)(m0 + srow)      * CDIM + k0 + scol], (char*)As + wid * 2048);
        GLOAD16(&A[(size_t)(m0 + srow + 16) * CDIM + k0 + scol], (char*)As + wid * 2048 + 1024);
        GLOAD16(&B[(size_t)(n0 + srow)      * CDIM + k0 + scol], (char*)Bs + wid * 2048);
        GLOAD16(&B[(size_t)(n0 + srow + 16) * CDIM + k0 + scol], (char*)Bs + wid * 2048 + 1024);
        __syncthreads();

        bf16x8 af[4], bfr[4];
        #pragma unroll
        for (int f = 0; f < 4; ++f) {
            af[f]  = *(const bf16x8*)&As[(wr * 64 + f * 16 + l15) * 32 + l4 * 8];
            bfr[f] = *(const bf16x8*)&Bs[(wc * 64 + f * 16 + l15) * 32 + l4 * 8];
        }
        #pragma unroll
        for (int i = 0; i < 4; ++i)
            #pragma unroll
            for (int j = 0; j < 4; ++j)
                acc[i][j] = __builtin_amdgcn_mfma_f32_16x16x32_bf16(af[i], bfr[j], acc[i][j], 0, 0, 0);
    }

    float bn[4];
    #pragma unroll
    for (int j = 0; j < 4; ++j) bn[j] = bias[n0 + wc * 64 + j * 16 + l15];

    if (z == 2) {
        // transposed write: vT[n][m], 4 consecutive m per lane -> 8B stores
        #pragma unroll
        for (int i = 0; i < 4; ++i)
            #pragma unroll
            for (int j = 0; j < 4; ++j) {
                const int n = n0 + wc * 64 + j * 16 + l15;
                const int mb = m0 + wr * 64 + i * 16 + l4 * 4;
                u16x4 pk;
                #pragma unroll
                for (int r = 0; r < 4; ++r) pk[r] = f2bf(acc[i][j][r] + bn[j]);
                *(u16x4*)&o2[(size_t)n * SEQ + mb] = pk;
            }
    } else {
        // RoPE fused: pair (d, d^1) lives in adjacent lanes (n bit0 == l15 bit0)
        ushort* outp = z == 0 ? o0 : o1;
        #pragma unroll
        for (int i = 0; i < 4; ++i)
            #pragma unroll
            for (int j = 0; j < 4; ++j) {
                const int n  = n0 + wc * 64 + j * 16 + l15;
                const int fi = (n & 127) >> 1;
                const bool odd = (n & 1) != 0;
                #pragma unroll
                for (int r = 0; r < 4; ++r) {
                    const int m = m0 + wr * 64 + i * 16 + l4 * 4 + r;
                    const float val     = acc[i][j][r] + bn[j];
                    const float partner = __shfl_xor(val, 1);
                    const float c = cosT[m * 64 + fi];
                    const float s = sinT[m * 64 + fi];
                    const float res = odd ? (partner * s + val * c)
                                          : (val * c - partner * s);
                    outp[(size_t)m * CDIM + n] = f2bf(res);
                }
            }
    }
}

// ------------------------------------------------------ MFMA flash attention
// grid (32 q-tiles reversed, 16 heads), 256 threads = 4 waves (2x2).
// V comes in pre-transposed: vT[d_global][t]. T14 async K/V staging.
__global__ __launch_bounds__(256) void flash_attn_mfma(const ushort* __restrict__ qb,
                                                       const ushort* __restrict__ kb,
                                                       const ushort* __restrict__ vT,
                                                       ushort* __restrict__ ao)
{
    __shared__ ushort Ks[64 * 136];    // row stride 272 B
    __shared__ ushort VTs[128 * 72];   // [d][kv], row stride 144 B
    __shared__ float  S_lds[64 * 68];
    __shared__ ushort Ps[64 * 72];
    __shared__ float  rowM[64], rowL[64], rowF[64];

    const int tid  = threadIdx.x;
    const int lane = tid & 63, wid = tid >> 6;
    const int wr = wid >> 1, wc = wid & 1;
    const int l4 = lane >> 4, l15 = lane & 15;
    const int h = blockIdx.y;
    const int qt = gridDim.x - 1 - blockIdx.x;   // longest blocks dispatch first
    const int q0 = qt * 64;

    if (tid < 64) { rowM[tid] = -INFINITY; rowL[tid] = 0.f; }

    // Q fragments in registers, reused across all K-tiles
    bf16x8 qf[2][4];
    #pragma unroll
    for (int fm = 0; fm < 2; ++fm)
        #pragma unroll
        for (int ks = 0; ks < 4; ++ks) {
            const int row = q0 + wr * 32 + fm * 16 + l15;
            const int col = h * DHEAD + ks * 32 + l4 * 8;
            qf[fm][ks] = *(const bf16x8*)&qb[(size_t)row * CDIM + col];
        }

    f32x4 acc_o[2][4];
    #pragma unroll
    for (int fm = 0; fm < 2; ++fm)
        #pragma unroll
        for (int fn = 0; fn < 4; ++fn) acc_o[fm][fn] = 0.f;

    // T14: issue-early K/V staging registers
    const int rK = tid >> 4,  cK = (tid & 15) * 8;
    const int rV = tid >> 3,  cV = (tid & 7) * 8;
    u16x8 kreg[4], vreg[4];

    // prologue: issue loads for kt=0
    #pragma unroll
    for (int i2 = 0; i2 < 4; ++i2)
        kreg[i2] = *(const u16x8*)&kb[(size_t)(rK + i2 * 16) * CDIM + h * DHEAD + cK];
    #pragma unroll
    for (int i2 = 0; i2 < 4; ++i2)
        vreg[i2] = *(const u16x8*)&vT[(size_t)(h * DHEAD + rV + i2 * 32) * SEQ + cV];

    for (int kt = 0; kt <= qt; ++kt) {
        __syncthreads();   // previous PV done before overwriting LDS

        // ---- write staged K/V regs -> LDS
        #pragma unroll
        for (int i2 = 0; i2 < 4; ++i2)
            *(u16x8*)&Ks[(rK + i2 * 16) * 136 + cK] = kreg[i2];
        #pragma unroll
        for (int i2 = 0; i2 < 4; ++i2)
            *(u16x8*)&VTs[(rV + i2 * 32) * 72 + cV] = vreg[i2];
        __syncthreads();

        // ---- S = Q K^T  (each wave: 32x32 of the 64x64 tile)
        f32x4 sacc[2][2];
        #pragma unroll
        for (int fm = 0; fm < 2; ++fm)
            #pragma unroll
            for (int fn = 0; fn < 2; ++fn) sacc[fm][fn] = 0.f;
        #pragma unroll
        for (int ks = 0; ks < 4; ++ks) {
            bf16x8 kf[2];
            #pragma unroll
            for (int fn = 0; fn < 2; ++fn)
                kf[fn] = *(const bf16x8*)&Ks[(wc * 32 + fn * 16 + l15) * 136 + ks * 32 + l4 * 8];
            #pragma unroll
            for (int fm = 0; fm < 2; ++fm)
                #pragma unroll
                for (int fn = 0; fn < 2; ++fn)
                    sacc[fm][fn] = __builtin_amdgcn_mfma_f32_16x16x32_bf16(qf[fm][ks], kf[fn], sacc[fm][fn], 0, 0, 0);
        }

        // ---- T14: issue next tile's K/V loads (fly under softmax+PV)
        if (kt < qt) {
            #pragma unroll
            for (int i2 = 0; i2 < 4; ++i2)
                kreg[i2] = *(const u16x8*)&kb[(size_t)((kt + 1) * 64 + rK + i2 * 16) * CDIM + h * DHEAD + cK];
            #pragma unroll
            for (int i2 = 0; i2 < 4; ++i2)
                vreg[i2] = *(const u16x8*)&vT[(size_t)(h * DHEAD + rV + i2 * 32) * SEQ + (kt + 1) * 64 + cV];
        }

        #pragma unroll
        for (int fm = 0; fm < 2; ++fm)
            #pragma unroll
            for (int fn = 0; fn < 2; ++fn)
                #pragma unroll
                for (int r = 0; r < 4; ++r) {
                    const int srow = wr * 32 + fm * 16 + l4 * 4 + r;
                    const int scol = wc * 32 + fn * 16 + l15;
                    float sv = sacc[fm][fn][r] * SCALE;
                    if (kt == qt && scol > srow) sv = -INFINITY;
                    S_lds[srow * 68 + scol] = sv;
                }
        __syncthreads();

        // ---- online softmax: 4 lanes per row
        {
            const int srow = tid >> 2;
            const int c0   = (tid & 3) * 16;
            float vals[16];
            #pragma unroll
            for (int c = 0; c < 16; ++c) vals[c] = S_lds[srow * 68 + c0 + c];
            float mt = vals[0];
            #pragma unroll
            for (int c = 1; c < 16; ++c) mt = fmaxf(mt, vals[c]);
            mt = fmaxf(mt, __shfl_xor(mt, 1));
            mt = fmaxf(mt, __shfl_xor(mt, 2));
            const float mold = rowM[srow];
            const float mnew = fmaxf(mold, mt);
            float sum = 0.f;
            ushort pb[16];
            #pragma unroll
            for (int c = 0; c < 16; ++c) {
                const float p = exp2f((vals[c] - mnew) * LOG2E);
                sum += p;
                pb[c] = f2bf(p);
            }
            sum += __shfl_xor(sum, 1);
            sum += __shfl_xor(sum, 2);
            u16x8 w0, w1;
            #pragma unroll
            for (int c = 0; c < 8; ++c) { w0[c] = pb[c]; w1[c] = pb[c + 8]; }
            *(u16x8*)&Ps[srow * 72 + c0]     = w0;
            *(u16x8*)&Ps[srow * 72 + c0 + 8] = w1;
            if ((tid & 3) == 0) {
                const float fac = exp2f((mold - mnew) * LOG2E);
                rowF[srow] = fac;
                rowL[srow] = rowL[srow] * fac + sum;
                rowM[srow] = mnew;
            }
        }
        __syncthreads();

        // ---- rescale O, then O += P V
        float frv[2][4];
        #pragma unroll
        for (int fm = 0; fm < 2; ++fm)
            #pragma unroll
            for (int r = 0; r < 4; ++r)
                frv[fm][r] = rowF[wr * 32 + fm * 16 + l4 * 4 + r];
        #pragma unroll
        for (int fm = 0; fm < 2; ++fm)
            #pragma unroll
            for (int fn = 0; fn < 4; ++fn)
                #pragma unroll
                for (int r = 0; r < 4; ++r) acc_o[fm][fn][r] *= frv[fm][r];

        #pragma unroll
        for (int ks = 0; ks < 2; ++ks) {
            bf16x8 pa[2];
            #pragma unroll
            for (int fm = 0; fm < 2; ++fm)
                pa[fm] = *(const bf16x8*)&Ps[(wr * 32 + fm * 16 + l15) * 72 + ks * 32 + l4 * 8];
            #pragma unroll
            for (int fn = 0; fn < 4; ++fn) {
                bf16x8 vf = *(const bf16x8*)&VTs[(wc * 64 + fn * 16 + l15) * 72 + ks * 32 + l4 * 8];
                #pragma unroll
                for (int fm = 0; fm < 2; ++fm)
                    acc_o[fm][fn] = __builtin_amdgcn_mfma_f32_16x16x32_bf16(pa[fm], vf, acc_o[fm][fn], 0, 0, 0);
            }
        }
    }

    // ---- epilogue: O /= rowL, store bf16
    #pragma unroll
    for (int fm = 0; fm < 2; ++fm)
        #pragma unroll
        for (int r = 0; r < 4; ++r) {
            const int lrow = wr * 32 + fm * 16 + l4 * 4 + r;
            const float invl = 1.f / rowL[lrow];
            #pragma unroll
            for (int fn = 0; fn < 4; ++fn) {
                const int gcol = h * DHEAD + wc * 64 + fn * 16 + l15;
                ao[(size_t)(q0 + lrow) * CDIM + gcol] = f2bf(acc_o[fm][fn][r] * invl);
            }
        }
}

extern "C" void kernel_launch(void* const* d_in, const int* in_sizes, int n_in,
                              void* d_out, int out_size, void* d_ws, size_t ws_size,
                              hipStream_t stream) {
    const float* x    = (const float*)d_in[0];
    const float* wq   = (const float*)d_in[1];
    const float* bq   = (const float*)d_in[2];
    const float* wk   = (const float*)d_in[3];
    const float* bk   = (const float*)d_in[4];
    const float* wv   = (const float*)d_in[5];
    const float* bv   = (const float*)d_in[6];
    const float* wp   = (const float*)d_in[7];
    const float* bp   = (const float*)d_in[8];
    const float* cosT = (const float*)d_in[9];
    const float* sinT = (const float*)d_in[10];

    const size_t mat = (size_t)SEQ * CDIM;   // 4M elements
    ushort* xb  = (ushort*)d_ws;             // also reused as attn output
    ushort* w0  = xb  + mat;
    ushort* w1  = w0  + mat;
    ushort* w2  = w1  + mat;
    ushort* w3  = w2  + mat;
    ushort* qbb = w3  + mat;
    ushort* kbb = qbb + mat;
    ushort* vTb = kbb + mat;
    ushort* aob = xb;            // x (bf16) dead after gemm_qkv

    const int n8 = (int)(mat / 8);

    f2bf5_kernel<<<dim3(n8 / 256, 5), 256, 0, stream>>>(x, wq, wk, wv, wp,
                                                        xb, w0, w1, w2, w3);

    gemm_qkv<<<dim3(16, 16, 3), 256, 0, stream>>>(xb, w0, w1, w2, bq, bk, bv,
                                                  cosT, sinT, qbb, kbb, vTb);

    flash_attn_mfma<<<dim3(SEQ / 64, NHEAD), 256, 0, stream>>>(qbb, kbb, vTb, aob);

    gemm_nt_mfma_f32<<<dim3(16, 16), 256, 0, stream>>>(aob, w3, bp, (float*)d_out);

    (void)in_sizes; (void)n_in; (void)out_size; (void)ws_size;
}